// Round 1
// baseline (1745.374 us; speedup 1.0000x reference)
//
#include <hip/hip_runtime.h>
#include <stdint.h>

// GruTl: tensor-factorized GRU, N=64, L=128, modes (32,16,8).
// Plan: kernel A precomputes XW[l,g,n,:] (all 256 CUs, bf16/f32 staging in ws),
// kernel B scans over L with one block per batch sample (h kept in LDS).
// Fallback fused kernel if ws too small.

constexpr int kN = 64;
constexpr int kL = 128;
constexpr int kA = 32, kB = 16, kC = 8;
constexpr int kBC = kB * kC;       // 128
constexpr int kTot = kA * kBC;     // 4096 elements per (n,l) tile
constexpr int kTS = kBC + 4;       // 132: padded LDS row stride per d (banks: 4d+idx -> <=2-way, free)
constexpr int kTh = 512;

namespace {

__device__ __forceinline__ int rfl(int v) { return __builtin_amdgcn_readfirstlane(v); }
__device__ __forceinline__ float bf2f(unsigned int u) { return __uint_as_float(u << 16); }
__device__ __forceinline__ unsigned int f2bf(float v) {
  unsigned int u = __float_as_uint(v);
  return (u + 0x7fffu + ((u >> 16) & 1u)) >> 16;   // round-to-nearest-even
}
__device__ __forceinline__ float sigmoid_f(float x) {
  return __fdividef(1.f, 1.f + __expf(-x));
}
__device__ __forceinline__ float tanh_f(float x) {
  return 1.f - __fdividef(2.f, 1.f + __expf(2.f * x));
}

__device__ __forceinline__ void load8(const float* p, float* v) {
  float4 a = ((const float4*)p)[0];
  float4 b = ((const float4*)p)[1];
  v[0]=a.x; v[1]=a.y; v[2]=a.z; v[3]=a.w;
  v[4]=b.x; v[5]=b.y; v[6]=b.z; v[7]=b.w;
}
__device__ __forceinline__ void load8(const unsigned short* p, float* v) {
  uint4 u = *(const uint4*)p;
  v[0]=bf2f(u.x & 0xffffu); v[1]=bf2f(u.x >> 16);
  v[2]=bf2f(u.y & 0xffffu); v[3]=bf2f(u.y >> 16);
  v[4]=bf2f(u.z & 0xffffu); v[5]=bf2f(u.z >> 16);
  v[6]=bf2f(u.w & 0xffffu); v[7]=bf2f(u.w >> 16);
}
__device__ __forceinline__ void store8(float* p, const float* v) {
  ((float4*)p)[0] = make_float4(v[0],v[1],v[2],v[3]);
  ((float4*)p)[1] = make_float4(v[4],v[5],v[6],v[7]);
}
__device__ __forceinline__ void store8(unsigned short* p, const float* v) {
  uint4 u;
  u.x = f2bf(v[0]) | (f2bf(v[1]) << 16);
  u.y = f2bf(v[2]) | (f2bf(v[3]) << 16);
  u.z = f2bf(v[4]) | (f2bf(v[5]) << 16);
  u.w = f2bf(v[6]) | (f2bf(v[7]) << 16);
  *(uint4*)p = u;
}

// t1[d][bc] = sum_a Wg[d*32+a] * src[a*128+bc]
// Wave-uniform d-group (via readfirstlane) so weight loads become s_loads.
__device__ __forceinline__ void mode1(const float* __restrict__ src,
                                      const float* __restrict__ Wg,
                                      float* __restrict__ t1, int tid) {
  const int w = rfl(tid >> 6);
  const int lane = tid & 63;
  const int bc = ((w & 1) << 6) | lane;   // 0..127
  const int dq = (w >> 1) << 3;           // d group of 8, wave-uniform
  float xr[kA];
#pragma unroll
  for (int a = 0; a < kA; ++a) xr[a] = src[a * kBC + bc];
  const float* wp = Wg + dq * kA;
#pragma unroll
  for (int dd = 0; dd < 8; ++dd) {
    float s = 0.f;
#pragma unroll
    for (int a = 0; a < kA; ++a) s += wp[dd * kA + a] * xr[a];
    t1[(dq + dd) * kTS + bc] = s;
  }
}

// t2[d][e][c] = sum_b Wg[e*16+b] * t1[d][b][c]   (e-half wave-uniform)
__device__ __forceinline__ void mode2(const float* __restrict__ t1,
                                      const float* __restrict__ Wg,
                                      float* __restrict__ t2, int tid) {
  const int w = rfl(tid >> 6);
  const int lane = tid & 63;
  const int d = ((w >> 1) << 3) | (lane >> 3);  // 0..31
  const int c = lane & 7;
  const int eh = (w & 1) << 3;                  // e half, wave-uniform
  float tr[kB];
#pragma unroll
  for (int b = 0; b < kB; ++b) tr[b] = t1[d * kTS + b * kC + c];
#pragma unroll
  for (int ee = 0; ee < 8; ++ee) {
    const int e = eh + ee;
    float s = 0.f;
#pragma unroll
    for (int b = 0; b < kB; ++b) s += Wg[e * kB + b] * tr[b];
    t2[d * kTS + e * kC + c] = s;
  }
}

// out8[f] = sum_c Wg[f*8+c] * t2[d][e][c]; thread -> d=tid>>4, e=tid&15
// (so out8 covers the contiguous slice [tid*8 .. tid*8+8) of the 4096 tile)
__device__ __forceinline__ void mode3(const float* __restrict__ t2,
                                      const float* __restrict__ Wg,
                                      float* __restrict__ out8, int tid) {
  const int e = tid & 15;
  const int d = tid >> 4;
  float tr[kC];
  load8(t2 + d * kTS + e * kC, tr);   // 528/32-byte offsets: float4-aligned
#pragma unroll
  for (int f = 0; f < kC; ++f) {
    float s = 0.f;
#pragma unroll
    for (int c = 0; c < kC; ++c) s += Wg[f * kC + c] * tr[c];
    out8[f] = s;
  }
}

// ---------------- kernel A: XW precompute, one block per (n,l) ----------------
template <typename WT>
__global__ __launch_bounds__(kTh) void xw_kernel(
    const float* __restrict__ x, const float* __restrict__ W1,
    const float* __restrict__ W2, const float* __restrict__ W3,
    WT* __restrict__ xw) {
  __shared__ float xs[kTot];
  __shared__ float t1[kA * kTS];
  __shared__ float t2[kA * kTS];
  const int tid = threadIdx.x;
  const int blk = blockIdx.x;                      // n*L + l
  const float4* xg = (const float4*)(x + (size_t)blk * kTot);
  float4* xs4 = (float4*)xs;
  xs4[tid] = xg[tid];
  xs4[tid + kTh] = xg[tid + kTh];
  __syncthreads();
#pragma unroll
  for (int g = 0; g < 3; ++g) {
    mode1(xs, W1 + g * kA * kA, t1, tid);
    __syncthreads();
    mode2(t1, W2 + g * kB * kB, t2, tid);
    __syncthreads();
    float v[kC];
    mode3(t2, W3 + g * kC * kC, v, tid);
    store8(xw + ((size_t)blk * 3 + g) * kTot + tid * kC, v);
    // no barrier needed: next-gate t1 writes are fenced by this gate's
    // post-mode2 barrier; next-gate t2 writes by next gate's post-mode1 barrier
  }
}

// ---------------- kernel B: sequential scan, one block per n ----------------
template <typename WT>
__global__ __launch_bounds__(kTh) void scan_kernel(
    const WT* __restrict__ xw, const float* __restrict__ U1,
    const float* __restrict__ U2, const float* __restrict__ U3,
    float* __restrict__ outs, float* __restrict__ hlast) {
  __shared__ float h[kTot];
  __shared__ float t1[kA * kTS];
  __shared__ float t2[kA * kTS];
  const int tid = threadIdx.x;
  const int n = blockIdx.x;
  for (int i = tid; i < kTot; i += kTh) h[i] = 0.f;
  __syncthreads();
  const int off = tid * kC;
  float* hp = h + off;
  const WT* xbase = xw + (size_t)n * kL * 3 * kTot + off;
  float xwv[3][kC];
  load8(xbase + 0 * kTot, xwv[0]);
  load8(xbase + 1 * kTot, xwv[1]);
  load8(xbase + 2 * kTot, xwv[2]);
  float hn[kC];
  for (int l = 0; l < kL; ++l) {
    // prefetch next step's xw while we compute this step (hides ~900cy HBM latency)
    const int ln = (l + 1 < kL) ? l + 1 : l;
    float xwn[3][kC];
    {
      const WT* xp = xbase + (size_t)ln * 3 * kTot;
      load8(xp, xwn[0]);
      load8(xp + kTot, xwn[1]);
      load8(xp + 2 * kTot, xwn[2]);
    }
    float hu[3][kC];
#pragma unroll
    for (int g = 0; g < 3; ++g) {
      mode1(h, U1 + g * kA * kA, t1, tid);
      __syncthreads();
      mode2(t1, U2 + g * kB * kB, t2, tid);
      __syncthreads();
      mode3(t2, U3 + g * kC * kC, hu[g], tid);
    }
    // elementwise GRU update on this thread's owned slice h[tid*8 .. +8)
    float ho[kC];
    load8(hp, ho);
#pragma unroll
    for (int f = 0; f < kC; ++f) {
      float z  = sigmoid_f(xwv[0][f] + hu[0][f]);
      float r  = sigmoid_f(xwv[1][f] + hu[1][f]);
      float hh = tanh_f(xwv[2][f] + r * hu[2][f]);
      hn[f] = z * ho[f] + (1.f - z) * hh;
    }
    store8(hp, hn);
    store8(outs + ((size_t)n * kL + l) * kTot + off, hn);
#pragma unroll
    for (int g = 0; g < 3; ++g)
#pragma unroll
      for (int f = 0; f < kC; ++f) xwv[g][f] = xwn[g][f];
    __syncthreads();   // h fully updated before next step's mode1
  }
  store8(hlast + (size_t)n * kTot + off, hn);
}

// ---------------- fallback: fully fused (no workspace) ----------------
__global__ __launch_bounds__(kTh) void fused_kernel(
    const float* __restrict__ x,
    const float* __restrict__ W1, const float* __restrict__ W2,
    const float* __restrict__ W3, const float* __restrict__ U1,
    const float* __restrict__ U2, const float* __restrict__ U3,
    float* __restrict__ outs, float* __restrict__ hlast) {
  __shared__ float h[kTot];
  __shared__ float xs[kTot];
  __shared__ float t1[kA * kTS];
  __shared__ float t2[kA * kTS];
  const int tid = threadIdx.x;
  const int n = blockIdx.x;
  for (int i = tid; i < kTot; i += kTh) h[i] = 0.f;
  const int off = tid * kC;
  float* hp = h + off;
  float hn[kC];
  for (int l = 0; l < kL; ++l) {
    const float4* xg = (const float4*)(x + ((size_t)n * kL + l) * kTot);
    float4 xa = xg[tid], xb = xg[tid + kTh];
    __syncthreads();                  // covers h-init / prev-step h writes & xs reads
    float4* xs4 = (float4*)xs;
    xs4[tid] = xa;
    xs4[tid + kTh] = xb;
    __syncthreads();
    float xwv[3][kC], hu[3][kC];
#pragma unroll
    for (int g = 0; g < 3; ++g) {
      mode1(xs, W1 + g * kA * kA, t1, tid);
      __syncthreads();
      mode2(t1, W2 + g * kB * kB, t2, tid);
      __syncthreads();
      mode3(t2, W3 + g * kC * kC, xwv[g], tid);
    }
#pragma unroll
    for (int g = 0; g < 3; ++g) {
      mode1(h, U1 + g * kA * kA, t1, tid);
      __syncthreads();
      mode2(t1, U2 + g * kB * kB, t2, tid);
      __syncthreads();
      mode3(t2, U3 + g * kC * kC, hu[g], tid);
    }
    float ho[kC];
    load8(hp, ho);
#pragma unroll
    for (int f = 0; f < kC; ++f) {
      float z  = sigmoid_f(xwv[0][f] + hu[0][f]);
      float r  = sigmoid_f(xwv[1][f] + hu[1][f]);
      float hh = tanh_f(xwv[2][f] + r * hu[2][f]);
      hn[f] = z * ho[f] + (1.f - z) * hh;
    }
    store8(hp, hn);
    store8(outs + ((size_t)n * kL + l) * kTot + off, hn);
  }
  store8(hlast + (size_t)n * kTot + off, hn);
}

}  // namespace

extern "C" void kernel_launch(void* const* d_in, const int* in_sizes, int n_in,
                              void* d_out, int out_size, void* d_ws, size_t ws_size,
                              hipStream_t stream) {
  const float* x  = (const float*)d_in[0];
  const float* W1 = (const float*)d_in[1];
  const float* W2 = (const float*)d_in[2];
  const float* W3 = (const float*)d_in[3];
  const float* U1 = (const float*)d_in[4];
  const float* U2 = (const float*)d_in[5];
  const float* U3 = (const float*)d_in[6];
  float* outs  = (float*)d_out;
  float* hlast = outs + (size_t)kN * kL * kTot;

  const size_t need_f32  = (size_t)kN * kL * 3 * kTot * sizeof(float);   // ~403 MB
  const size_t need_bf16 = need_f32 / 2;                                 // ~201 MB

  if (ws_size >= need_f32) {
    xw_kernel<float><<<dim3(kN * kL), dim3(kTh), 0, stream>>>(x, W1, W2, W3,
                                                              (float*)d_ws);
    scan_kernel<float><<<dim3(kN), dim3(kTh), 0, stream>>>(
        (const float*)d_ws, U1, U2, U3, outs, hlast);
  } else if (ws_size >= need_bf16) {
    xw_kernel<unsigned short><<<dim3(kN * kL), dim3(kTh), 0, stream>>>(
        x, W1, W2, W3, (unsigned short*)d_ws);
    scan_kernel<unsigned short><<<dim3(kN), dim3(kTh), 0, stream>>>(
        (const unsigned short*)d_ws, U1, U2, U3, outs, hlast);
  } else {
    fused_kernel<<<dim3(kN), dim3(kTh), 0, stream>>>(x, W1, W2, W3, U1, U2, U3,
                                                     outs, hlast);
  }
}

// Round 2
// 718.634 us; speedup vs baseline: 2.4287x; 2.4287x over previous
//
#include <hip/hip_runtime.h>
#include <stdint.h>

// GruTl: tensor-factorized GRU, N=64, L=128, modes (32,16,8) -> (32,16,8).
// R2: MFMA rewrite. Per gate: hu = kron(U2,U3)-folded two-GEMM contraction.
//   GEMM1: t1[d][bc] = sum_a U1[d][a] * h[a][bc]      (16x16x32 bf16 MFMA)
//   GEMM2: hu[d][ef] = sum_bc t1[d][bc] * kronU[ef][bc]
// kron matrices precomputed once per launch into ws (bf16). XW precomputed by
// an MFMA kernel (same structure, W weights) into ws in scan-fragment order.
// h master state stays fp32 in registers; only MFMA inputs rounded to bf16.

constexpr int kN = 64;
constexpr int kL = 128;
constexpr int kA = 32, kB = 16, kC = 8;
constexpr int kBC = kB * kC;       // 128
constexpr int kTot = kA * kBC;     // 4096 elements per (n,l) tile
constexpr int kTS = kBC + 4;       // fused-fallback LDS stride
constexpr int kTh = 512;

constexpr int kHTS = 40;           // hT/xT row stride in bf16 (32 + 8 pad, 16B-aligned rows)
constexpr int kT1S = 136;          // t1L row stride in bf16 (128 + 8 pad)

typedef __attribute__((ext_vector_type(8))) short bf16x8;
typedef __attribute__((ext_vector_type(4))) float f32x4;

namespace {

__device__ __forceinline__ float bf2f(unsigned int u) { return __uint_as_float(u << 16); }
__device__ __forceinline__ unsigned int f2bf(float v) {
  unsigned int u = __float_as_uint(v);
  return (u + 0x7fffu + ((u >> 16) & 1u)) >> 16;   // round-to-nearest-even
}
__device__ __forceinline__ float sigmoid_f(float x) {
  return __fdividef(1.f, 1.f + __expf(-x));
}
__device__ __forceinline__ float tanh_f(float x) {
  return 1.f - __fdividef(2.f, 1.f + __expf(2.f * x));
}

__device__ __forceinline__ bf16x8 frag_from_lds(const unsigned short* p) {
  uint4 u = *(const uint4*)p;
  return __builtin_bit_cast(bf16x8, u);
}
// 8 consecutive f32 -> bf16 frag (element j = input j)
__device__ __forceinline__ bf16x8 frag_from_f32(const float* p) {
  float4 a = ((const float4*)p)[0];
  float4 b = ((const float4*)p)[1];
  uint4 u;
  u.x = f2bf(a.x) | (f2bf(a.y) << 16);
  u.y = f2bf(a.z) | (f2bf(a.w) << 16);
  u.z = f2bf(b.x) | (f2bf(b.y) << 16);
  u.w = f2bf(b.z) | (f2bf(b.w) << 16);
  return __builtin_bit_cast(bf16x8, u);
}
__device__ __forceinline__ uint2 pack4(const f32x4& a) {
  uint2 p;
  p.x = f2bf(a[0]) | (f2bf(a[1]) << 16);
  p.y = f2bf(a[2]) | (f2bf(a[3]) << 16);
  return p;
}

// ---------------- kron precompute: kW/kU[g][ef][bc] = M2[g][e][b]*M3[g][f][c]
__global__ void kron_kernel(const float* __restrict__ W2, const float* __restrict__ W3,
                            const float* __restrict__ U2, const float* __restrict__ U3,
                            unsigned short* __restrict__ kW, unsigned short* __restrict__ kU) {
  int i = blockIdx.x * 256 + threadIdx.x;           // 0 .. 98303
  const float* M2 = W2; const float* M3 = W3; unsigned short* dst = kW;
  int j = i;
  if (i >= 3 * 128 * 128) { M2 = U2; M3 = U3; dst = kU; j = i - 3 * 128 * 128; }
  int g = j >> 14, ef = (j >> 7) & 127, bc = j & 127;
  int e = ef >> 3, f = ef & 7, b = bc >> 3, c = bc & 7;
  float v = M2[(g * 16 + e) * 16 + b] * M3[(g * 8 + f) * 8 + c];
  dst[j] = (unsigned short)f2bf(v);
}

// Shared GEMM1: out1T[bc][d] = sum_a srcT[bc][a] * M1T[a][d], written as t1L[d][bc].
// Wave w owns bc-tile mt1=w; nt1 in {0,1}. a-frag = srcT row (w*16+r), cols q*8..+8.
__device__ __forceinline__ void gemm1(const unsigned short* __restrict__ srcT,
                                      const bf16x8 bW[3][2],
                                      unsigned short (*__restrict__ t1L)[kA * kT1S],
                                      int w, int q, int r) {
  bf16x8 ah = frag_from_lds(srcT + (w * 16 + r) * kHTS + q * 8);
#pragma unroll
  for (int g = 0; g < 3; ++g) {
#pragma unroll
    for (int nt = 0; nt < 2; ++nt) {
      f32x4 acc = {0.f, 0.f, 0.f, 0.f};
      acc = __builtin_amdgcn_mfma_f32_16x16x32_bf16(ah, bW[g][nt], acc, 0, 0, 0);
      // D[bc = w*16+q*4+i][d = nt*16+r] -> t1L[g][d][bc], 4 consecutive bc
      *(uint2*)&t1L[g][(nt * 16 + r) * kT1S + w * 16 + q * 4] = pack4(acc);
    }
  }
}

// Shared GEMM2: out2[g][mt] D-frags: out[d = mt*16+q*4+i][ef = w*16+r]
__device__ __forceinline__ void gemm2(const unsigned short (*__restrict__ t1L)[kA * kT1S],
                                      const bf16x8 bK[3][4],
                                      f32x4 out2[3][2],
                                      int w, int q, int r) {
#pragma unroll
  for (int g = 0; g < 3; ++g) {
#pragma unroll
    for (int mt = 0; mt < 2; ++mt) {
      f32x4 acc = {0.f, 0.f, 0.f, 0.f};
#pragma unroll
      for (int kc = 0; kc < 4; ++kc) {
        bf16x8 af = frag_from_lds(&t1L[g][(mt * 16 + r) * kT1S + kc * 32 + q * 8]);
        acc = __builtin_amdgcn_mfma_f32_16x16x32_bf16(af, bK[g][kc], acc, 0, 0, 0);
      }
      out2[g][mt] = acc;
    }
  }
}

// Load B-frags: bK[g][kc] from kron (bf16 global), bW[g][nt] from M1 (f32 global)
__device__ __forceinline__ void load_bfrags(const unsigned short* __restrict__ kron,
                                            const float* __restrict__ M1,
                                            bf16x8 bK[3][4], bf16x8 bW[3][2],
                                            int w, int q, int r) {
#pragma unroll
  for (int g = 0; g < 3; ++g) {
#pragma unroll
    for (int kc = 0; kc < 4; ++kc)
      bK[g][kc] = frag_from_lds(kron + ((g * 128 + w * 16 + r) * 128 + kc * 32 + q * 8));
#pragma unroll
    for (int nt = 0; nt < 2; ++nt)
      bW[g][nt] = frag_from_f32(M1 + (g * 32 + nt * 16 + r) * 32 + q * 8);
  }
}

// ---------------- kernel A: XW precompute via MFMA, one block per (n,l) --------
__global__ __launch_bounds__(kTh) void xw_mfma(
    const float* __restrict__ x, const float* __restrict__ W1,
    const unsigned short* __restrict__ kW, unsigned short* __restrict__ xw) {
  __shared__ __align__(16) unsigned short xT[kBC * kHTS];
  __shared__ __align__(16) unsigned short t1L[3][kA * kT1S];
  const int tid = threadIdx.x;
  const int blk = blockIdx.x;                       // n*L + t
  const int w = tid >> 6, l = tid & 63, q = l >> 4, r = l & 15;

  bf16x8 bK[3][4], bW[3][2];
  load_bfrags(kW, W1, bK, bW, w, q, r);

  // stage x tile -> xT[bc][a] (bf16). thread: fixed bc, 8 consecutive a.
  {
    const int bc = tid & 127, a0 = (tid >> 7) * 8;
    const float* xg = x + (size_t)blk * kTot + bc;
    uint4 u;
    u.x = f2bf(xg[(a0 + 0) * kBC]) | (f2bf(xg[(a0 + 1) * kBC]) << 16);
    u.y = f2bf(xg[(a0 + 2) * kBC]) | (f2bf(xg[(a0 + 3) * kBC]) << 16);
    u.z = f2bf(xg[(a0 + 4) * kBC]) | (f2bf(xg[(a0 + 5) * kBC]) << 16);
    u.w = f2bf(xg[(a0 + 6) * kBC]) | (f2bf(xg[(a0 + 7) * kBC]) << 16);
    *(uint4*)&xT[bc * kHTS + a0] = u;
  }
  __syncthreads();
  gemm1(xT, bW, t1L, w, q, r);
  __syncthreads();
  f32x4 out2[3][2];
  gemm2(t1L, bK, out2, w, q, r);
  // store fragment-ordered bf16: pos = tid*8 + mt*4 + i
#pragma unroll
  for (int g = 0; g < 3; ++g) {
    uint4 u;
    uint2 p0 = pack4(out2[g][0]), p1 = pack4(out2[g][1]);
    u.x = p0.x; u.y = p0.y; u.z = p1.x; u.w = p1.y;
    *(uint4*)(xw + ((size_t)blk * 3 + g) * kTot + tid * 8) = u;
  }
}

// ---------------- kernel B: MFMA scan, one block per n ----------------
__global__ __launch_bounds__(kTh) void scan_mfma(
    const unsigned short* __restrict__ xw, const float* __restrict__ U1,
    const unsigned short* __restrict__ kU,
    float* __restrict__ outs, float* __restrict__ hlast) {
  __shared__ __align__(16) unsigned short hT[kBC * kHTS];
  __shared__ __align__(16) unsigned short t1L[3][kA * kT1S];
  const int tid = threadIdx.x;
  const int n = blockIdx.x;
  const int w = tid >> 6, l = tid & 63, q = l >> 4, r = l & 15;

  bf16x8 bK[3][4], bW[3][2];
  load_bfrags(kU, U1, bK, bW, w, q, r);

  // zero hT
  for (int i = tid; i < kBC * kHTS / 2; i += kTh) ((unsigned int*)hT)[i] = 0u;
  float hreg[2][4] = {{0.f, 0.f, 0.f, 0.f}, {0.f, 0.f, 0.f, 0.f}};

  const unsigned short* xp = xw + (size_t)n * kL * 3 * kTot + tid * 8;
  unsigned int xc[3][4];
#pragma unroll
  for (int g = 0; g < 3; ++g) {
    uint4 u = *(const uint4*)(xp + g * kTot);
    xc[g][0] = u.x; xc[g][1] = u.y; xc[g][2] = u.z; xc[g][3] = u.w;
  }
  __syncthreads();

  for (int t = 0; t < kL; ++t) {
    // prefetch next step's xw
    unsigned int xn[3][4];
    {
      const unsigned short* xq = xp + (size_t)((t + 1 < kL) ? t + 1 : t) * 3 * kTot;
#pragma unroll
      for (int g = 0; g < 3; ++g) {
        uint4 u = *(const uint4*)(xq + g * kTot);
        xn[g][0] = u.x; xn[g][1] = u.y; xn[g][2] = u.z; xn[g][3] = u.w;
      }
    }
    gemm1(hT, bW, t1L, w, q, r);
    __syncthreads();
    f32x4 hu[3][2];
    gemm2(t1L, bK, hu, w, q, r);

    // elementwise GRU on owned elements (d = mt*16+q*4+i, ef = w*16+r)
    const size_t obase = ((size_t)n * kL + t) * kTot + w * 16 + r;
#pragma unroll
    for (int mt = 0; mt < 2; ++mt) {
#pragma unroll
      for (int i = 0; i < 4; ++i) {
        const int e2 = mt * 4 + i;
        float x0 = bf2f((e2 & 1) ? (xc[0][e2 >> 1] >> 16) : (xc[0][e2 >> 1] & 0xffffu));
        float x1 = bf2f((e2 & 1) ? (xc[1][e2 >> 1] >> 16) : (xc[1][e2 >> 1] & 0xffffu));
        float x2 = bf2f((e2 & 1) ? (xc[2][e2 >> 1] >> 16) : (xc[2][e2 >> 1] & 0xffffu));
        float z  = sigmoid_f(x0 + hu[0][mt][i]);
        float rr = sigmoid_f(x1 + hu[1][mt][i]);
        float hc = tanh_f(x2 + rr * hu[2][mt][i]);
        float hn = z * hreg[mt][i] + (1.f - z) * hc;
        hreg[mt][i] = hn;
        outs[obase + (size_t)(mt * 16 + q * 4 + i) * kBC] = hn;
      }
      // write updated h (bf16) for next step's GEMM1
      uint2 p;
      p.x = f2bf(hreg[mt][0]) | (f2bf(hreg[mt][1]) << 16);
      p.y = f2bf(hreg[mt][2]) | (f2bf(hreg[mt][3]) << 16);
      *(uint2*)&hT[(w * 16 + r) * kHTS + mt * 16 + q * 4] = p;
    }
#pragma unroll
    for (int g = 0; g < 3; ++g)
#pragma unroll
      for (int u = 0; u < 4; ++u) xc[g][u] = xn[g][u];
    __syncthreads();
  }
#pragma unroll
  for (int mt = 0; mt < 2; ++mt)
#pragma unroll
    for (int i = 0; i < 4; ++i)
      hlast[(size_t)n * kTot + (size_t)(mt * 16 + q * 4 + i) * kBC + w * 16 + r] =
          hreg[mt][i];
}

// ---------------- fallback: fully fused fp32 (validated structure, slow) -------
__device__ __forceinline__ int rfl(int v) { return __builtin_amdgcn_readfirstlane(v); }

__device__ __forceinline__ void load8f(const float* p, float* v) {
  float4 a = ((const float4*)p)[0];
  float4 b = ((const float4*)p)[1];
  v[0]=a.x; v[1]=a.y; v[2]=a.z; v[3]=a.w;
  v[4]=b.x; v[5]=b.y; v[6]=b.z; v[7]=b.w;
}
__device__ __forceinline__ void store8f(float* p, const float* v) {
  ((float4*)p)[0] = make_float4(v[0],v[1],v[2],v[3]);
  ((float4*)p)[1] = make_float4(v[4],v[5],v[6],v[7]);
}

__device__ __forceinline__ void mode1(const float* __restrict__ src,
                                      const float* __restrict__ Wg,
                                      float* __restrict__ t1, int tid) {
  const int w = rfl(tid >> 6);
  const int lane = tid & 63;
  const int bc = ((w & 1) << 6) | lane;
  const int dq = (w >> 1) << 3;
  float xr[kA];
#pragma unroll
  for (int a = 0; a < kA; ++a) xr[a] = src[a * kBC + bc];
  const float* wp = Wg + dq * kA;
#pragma unroll
  for (int dd = 0; dd < 8; ++dd) {
    float s = 0.f;
#pragma unroll
    for (int a = 0; a < kA; ++a) s += wp[dd * kA + a] * xr[a];
    t1[(dq + dd) * kTS + bc] = s;
  }
}
__device__ __forceinline__ void mode2(const float* __restrict__ t1,
                                      const float* __restrict__ Wg,
                                      float* __restrict__ t2, int tid) {
  const int w = rfl(tid >> 6);
  const int lane = tid & 63;
  const int d = ((w >> 1) << 3) | (lane >> 3);
  const int c = lane & 7;
  const int eh = (w & 1) << 3;
  float tr[kB];
#pragma unroll
  for (int b = 0; b < kB; ++b) tr[b] = t1[d * kTS + b * kC + c];
#pragma unroll
  for (int ee = 0; ee < 8; ++ee) {
    const int e = eh + ee;
    float s = 0.f;
#pragma unroll
    for (int b = 0; b < kB; ++b) s += Wg[e * kB + b] * tr[b];
    t2[d * kTS + e * kC + c] = s;
  }
}
__device__ __forceinline__ void mode3(const float* __restrict__ t2,
                                      const float* __restrict__ Wg,
                                      float* __restrict__ out8, int tid) {
  const int e = tid & 15;
  const int d = tid >> 4;
  float tr[kC];
  load8f(t2 + d * kTS + e * kC, tr);
#pragma unroll
  for (int f = 0; f < kC; ++f) {
    float s = 0.f;
#pragma unroll
    for (int c = 0; c < kC; ++c) s += Wg[f * kC + c] * tr[c];
    out8[f] = s;
  }
}

__global__ __launch_bounds__(kTh) void fused_kernel(
    const float* __restrict__ x,
    const float* __restrict__ W1, const float* __restrict__ W2,
    const float* __restrict__ W3, const float* __restrict__ U1,
    const float* __restrict__ U2, const float* __restrict__ U3,
    float* __restrict__ outs, float* __restrict__ hlast) {
  __shared__ float h[kTot];
  __shared__ float xs[kTot];
  __shared__ float t1[kA * kTS];
  __shared__ float t2[kA * kTS];
  const int tid = threadIdx.x;
  const int n = blockIdx.x;
  for (int i = tid; i < kTot; i += kTh) h[i] = 0.f;
  const int off = tid * kC;
  float* hp = h + off;
  float hn[kC];
  for (int l = 0; l < kL; ++l) {
    const float4* xg = (const float4*)(x + ((size_t)n * kL + l) * kTot);
    float4 xa = xg[tid], xb = xg[tid + kTh];
    __syncthreads();
    float4* xs4 = (float4*)xs;
    xs4[tid] = xa;
    xs4[tid + kTh] = xb;
    __syncthreads();
    float xwv[3][kC], hu[3][kC];
#pragma unroll
    for (int g = 0; g < 3; ++g) {
      mode1(xs, W1 + g * kA * kA, t1, tid);
      __syncthreads();
      mode2(t1, W2 + g * kB * kB, t2, tid);
      __syncthreads();
      mode3(t2, W3 + g * kC * kC, xwv[g], tid);
    }
#pragma unroll
    for (int g = 0; g < 3; ++g) {
      mode1(h, U1 + g * kA * kA, t1, tid);
      __syncthreads();
      mode2(t1, U2 + g * kB * kB, t2, tid);
      __syncthreads();
      mode3(t2, U3 + g * kC * kC, hu[g], tid);
    }
    float ho[kC];
    load8f(hp, ho);
#pragma unroll
    for (int f = 0; f < kC; ++f) {
      float z  = sigmoid_f(xwv[0][f] + hu[0][f]);
      float rr = sigmoid_f(xwv[1][f] + hu[1][f]);
      float hh = tanh_f(xwv[2][f] + rr * hu[2][f]);
      hn[f] = z * ho[f] + (1.f - z) * hh;
    }
    store8f(hp, hn);
    store8f(outs + ((size_t)n * kL + l) * kTot + off, hn);
  }
  store8f(hlast + (size_t)n * kTot + off, hn);
}

}  // namespace

extern "C" void kernel_launch(void* const* d_in, const int* in_sizes, int n_in,
                              void* d_out, int out_size, void* d_ws, size_t ws_size,
                              hipStream_t stream) {
  const float* x  = (const float*)d_in[0];
  const float* W1 = (const float*)d_in[1];
  const float* W2 = (const float*)d_in[2];
  const float* W3 = (const float*)d_in[3];
  const float* U1 = (const float*)d_in[4];
  const float* U2 = (const float*)d_in[5];
  const float* U3 = (const float*)d_in[6];
  float* outs  = (float*)d_out;
  float* hlast = outs + (size_t)kN * kL * kTot;

  const size_t kron_elems = 3 * 128 * 128;                    // per kron matrix
  const size_t kron_bytes = 2 * kron_elems * sizeof(unsigned short);   // 96 KB
  const size_t xw_bytes   = (size_t)kN * kL * 3 * kTot * 2;   // ~201 MB bf16

  if (ws_size >= kron_bytes + xw_bytes) {
    unsigned short* kW  = (unsigned short*)d_ws;
    unsigned short* kU  = kW + kron_elems;
    unsigned short* xww = kU + kron_elems;
    kron_kernel<<<dim3(384), dim3(256), 0, stream>>>(W2, W3, U2, U3, kW, kU);
    xw_mfma<<<dim3(kN * kL), dim3(kTh), 0, stream>>>(x, W1, kW, xww);
    scan_mfma<<<dim3(kN), dim3(kTh), 0, stream>>>(xww, U1, kU, outs, hlast);
  } else {
    fused_kernel<<<dim3(kN), dim3(kTh), 0, stream>>>(x, W1, W2, W3, U1, U2, U3,
                                                     outs, hlast);
  }
}